// Round 1
// baseline (3351.303 us; speedup 1.0000x reference)
//
#include <hip/hip_runtime.h>
#include <cstddef>

#define NMAT 512
#define NPTS 4096
#define MRHS 12
#define NCHUNK 8
#define ECH 128   // 1024 / NCHUNK

// ---------------- Stage 1: partials[chunk] = sum_{e in chunk} r[e] * M[e] ----------------
__global__ void __launch_bounds__(256) k_partial(const float* __restrict__ M,
                                                 const float* __restrict__ r,
                                                 float* __restrict__ partials) {
    __shared__ float rs[ECH];
    const int chunk = blockIdx.y;
    const int idx4 = blockIdx.x * 256 + threadIdx.x;   // 0..65535 (float4 index in 512x512)
    for (int i = threadIdx.x; i < ECH; i += 256) rs[i] = r[chunk * ECH + i];
    __syncthreads();
    const float4* __restrict__ M4 = (const float4*)M;
    const size_t base = (size_t)chunk * ECH * 65536u + (size_t)idx4;
    float ax = 0.f, ay = 0.f, az = 0.f, aw = 0.f;
#pragma unroll 4
    for (int e = 0; e < ECH; ++e) {
        float4 v = M4[base + (size_t)e * 65536u];
        float rv = rs[e];
        ax += rv * v.x; ay += rv * v.y; az += rv * v.z; aw += rv * v.w;
    }
    float4 o; o.x = ax; o.y = ay; o.z = az; o.w = aw;
    ((float4*)partials)[(size_t)chunk * 65536u + idx4] = o;
}

// ---------------- Stage 1b: A = constant_part + sum_c partials[c]; LU = A ----------------
__global__ void __launch_bounds__(256) k_combine(const float* __restrict__ partials,
                                                 const float* __restrict__ cpart,
                                                 float* __restrict__ A,
                                                 float* __restrict__ LU) {
    const int idx4 = blockIdx.x * 256 + threadIdx.x;
    const float4* p4 = (const float4*)partials;
    float4 a = ((const float4*)cpart)[idx4];
#pragma unroll
    for (int c = 0; c < NCHUNK; ++c) {
        float4 v = p4[(size_t)c * 65536u + idx4];
        a.x += v.x; a.y += v.y; a.z += v.z; a.w += v.w;
    }
    ((float4*)A)[idx4] = a;
    ((float4*)LU)[idx4] = a;
}

// ---------------- LU panel factor (no pivoting), NB=64, one block ----------------
// Panel p: cols [k0,k0+64), rows [k0,512). Panel held in LDS (<=128 KiB).
// L entries (strictly below diag) are streamed to global during the steps;
// U part (top 64x64 upper triangle incl diag) written back at the end.
__global__ void __launch_bounds__(1024) k_panel(float* __restrict__ LU, int k0) {
    __shared__ float sh[NMAT * 64];
    const int nr = NMAT - k0;
    const int tid = threadIdx.x;
    const int jj = tid & 63;
    const int ib = tid >> 6;     // 0..15
    for (int idx = tid; idx < nr * 64; idx += 1024) {
        int i = idx >> 6, c = idx & 63;
        sh[idx] = LU[(size_t)(k0 + i) * NMAT + k0 + c];
    }
    __syncthreads();
    for (int j = 0; j < 64; ++j) {
        float pivinv = 1.0f / sh[j * 64 + j];
        for (int i = ib; i < nr; i += 16) {
            if (i <= j) continue;
            float l = sh[i * 64 + j] * pivinv;
            if (jj == j) {
                LU[(size_t)(k0 + i) * NMAT + k0 + j] = l;       // store L column
            } else if (jj > j) {
                sh[i * 64 + jj] -= l * sh[j * 64 + jj];          // rank-1 update
            }
        }
        __syncthreads();
    }
    for (int idx = tid; idx < 64 * 64; idx += 1024) {
        int i = idx >> 6, c = idx & 63;
        if (c >= i) LU[(size_t)(k0 + i) * NMAT + k0 + c] = sh[i * 64 + c];
    }
}

// ---------------- U12 = L11^{-1} A12 (row block of U), per 64-col tile ----------------
__global__ void __launch_bounds__(256) k_trsm(float* __restrict__ LU, int k0) {
    __shared__ float L11[64 * 65];
    __shared__ float Y[64 * 65];
    const int k1 = k0 + 64;
    const int jc0 = k1 + blockIdx.x * 64;
    const int tid = threadIdx.x;
    for (int idx = tid; idx < 4096; idx += 256) {
        int i = idx >> 6, c = idx & 63;
        L11[i * 65 + c] = LU[(size_t)(k0 + i) * NMAT + k0 + c];
        Y[i * 65 + c]   = LU[(size_t)(k0 + i) * NMAT + jc0 + c];
    }
    __syncthreads();
    const int c = tid & 63, ib = tid >> 6;  // ib 0..3
    for (int t = 0; t < 64; ++t) {
        float yt = Y[t * 65 + c];
        for (int i = ib; i < 64; i += 4)
            if (i > t) Y[i * 65 + c] -= L11[i * 65 + t] * yt;
        __syncthreads();
    }
    for (int idx = tid; idx < 4096; idx += 256) {
        int i = idx >> 6, cc = idx & 63;
        LU[(size_t)(k0 + i) * NMAT + jc0 + cc] = Y[i * 65 + cc];
    }
}

// ---------------- A22 -= L21 @ U12, 64x64 tiles, 4x4 per thread ----------------
__global__ void __launch_bounds__(256) k_gemm(float* __restrict__ LU, int k0) {
    __shared__ float L21[64 * 65];
    __shared__ float Ys[64 * 65];
    const int k1 = k0 + 64;
    const int jc0 = k1 + blockIdx.x * 64;
    const int r0  = k1 + blockIdx.y * 64;
    const int tid = threadIdx.x;
    for (int idx = tid; idx < 4096; idx += 256) {
        int i = idx >> 6, c = idx & 63;
        L21[i * 65 + c] = LU[(size_t)(r0 + i) * NMAT + k0 + c];
        Ys[i * 65 + c]  = LU[(size_t)(k0 + i) * NMAT + jc0 + c];
    }
    __syncthreads();
    const int trow = tid >> 4, tcol = tid & 15;
    float acc[4][4];
#pragma unroll
    for (int rr = 0; rr < 4; ++rr) {
        float4 v = *(const float4*)&LU[(size_t)(r0 + 4 * trow + rr) * NMAT + jc0 + 4 * tcol];
        acc[rr][0] = v.x; acc[rr][1] = v.y; acc[rr][2] = v.z; acc[rr][3] = v.w;
    }
#pragma unroll 4
    for (int kk = 0; kk < 64; ++kk) {
        float b0 = Ys[kk * 65 + 4 * tcol + 0];
        float b1 = Ys[kk * 65 + 4 * tcol + 1];
        float b2 = Ys[kk * 65 + 4 * tcol + 2];
        float b3 = Ys[kk * 65 + 4 * tcol + 3];
#pragma unroll
        for (int rr = 0; rr < 4; ++rr) {
            float a = L21[(4 * trow + rr) * 65 + kk];
            acc[rr][0] -= a * b0; acc[rr][1] -= a * b1;
            acc[rr][2] -= a * b2; acc[rr][3] -= a * b3;
        }
    }
#pragma unroll
    for (int rr = 0; rr < 4; ++rr) {
        float4 v; v.x = acc[rr][0]; v.y = acc[rr][1]; v.z = acc[rr][2]; v.w = acc[rr][3];
        *(float4*)&LU[(size_t)(r0 + 4 * trow + rr) * NMAT + jc0 + 4 * tcol] = v;
    }
}

// ---------------- triangular solves for 12 RHS: one block (1 wave) per column ----------------
// mode 0: b = e_{500+c}, W = x      mode 1: b = B[:,c], W += x
__global__ void __launch_bounds__(64) k_solve(const float* __restrict__ LU,
                                              const float* __restrict__ B,
                                              float* __restrict__ W, int mode) {
    const int c = blockIdx.x;
    const int lane = threadIdx.x;
    float y[8];
#pragma unroll
    for (int s = 0; s < 8; ++s) {
        int row = s * 64 + lane;
        if (mode) y[s] = B[row * MRHS + c];
        else      y[s] = (row == 500 + c) ? 1.0f : 0.0f;
    }
    // forward: L (unit diag) y = b
#pragma unroll
    for (int js = 0; js < 8; ++js) {
        for (int jl = 0; jl < 64; ++jl) {
            const int j = js * 64 + jl;
            float yj = __shfl(y[js], jl);
            if (lane > jl) y[js] -= LU[(size_t)(js * 64 + lane) * NMAT + j] * yj;
#pragma unroll
            for (int s = js + 1; s < 8; ++s)
                y[s] -= LU[(size_t)(s * 64 + lane) * NMAT + j] * yj;
        }
    }
    // backward: U x = y
#pragma unroll
    for (int js = 7; js >= 0; --js) {
        for (int jl = 63; jl >= 0; --jl) {
            const int j = js * 64 + jl;
            float xj = __shfl(y[js], jl) / LU[(size_t)j * NMAT + j];
            if (lane == jl) y[js] = xj;
            if (lane < jl) y[js] -= LU[(size_t)(js * 64 + lane) * NMAT + j] * xj;
#pragma unroll
            for (int s = 0; s < js; ++s)
                y[s] -= LU[(size_t)(s * 64 + lane) * NMAT + j] * xj;
        }
    }
#pragma unroll
    for (int s = 0; s < 8; ++s) {
        int row = s * 64 + lane;
        if (mode) W[row * MRHS + c] += y[s];
        else      W[row * MRHS + c] = y[s];
    }
}

// ---------------- residual R = I[:,500:512] - A @ W  (f64 accumulate) ----------------
__global__ void __launch_bounds__(64) k_resid(const float* __restrict__ A,
                                              const float* __restrict__ W,
                                              float* __restrict__ R) {
    const int row = blockIdx.x;
    const int lane = threadIdx.x;
    double acc[MRHS];
#pragma unroll
    for (int cc = 0; cc < MRHS; ++cc) acc[cc] = 0.0;
    for (int k = lane; k < NMAT; k += 64) {
        float a = A[(size_t)row * NMAT + k];
#pragma unroll
        for (int cc = 0; cc < MRHS; ++cc) acc[cc] += (double)a * (double)W[k * MRHS + cc];
    }
#pragma unroll
    for (int cc = 0; cc < MRHS; ++cc) {
        double v = acc[cc];
#pragma unroll
        for (int off = 32; off > 0; off >>= 1) v += __shfl_xor(v, off);
        if (lane == cc) R[row * MRHS + cc] = (float)(((row == 500 + cc) ? 1.0 : 0.0) - v);
    }
}

// ---------------- out[i][p] = sum_k W[i][k] * e[k][p], e = x reinterpreted (12,4096) ----------------
__global__ void __launch_bounds__(256) k_out(const float* __restrict__ W,
                                             const float* __restrict__ x,
                                             float* __restrict__ out) {
    const int p4 = blockIdx.x * 256 + threadIdx.x;  // 0..1023
    const int i = blockIdx.y;
    const float4* __restrict__ x4 = (const float4*)x;
    float ax = 0.f, ay = 0.f, az = 0.f, aw = 0.f;
#pragma unroll
    for (int k = 0; k < MRHS; ++k) {
        float w = W[i * MRHS + k];
        float4 v = x4[k * 1024 + p4];
        ax += w * v.x; ay += w * v.y; az += w * v.z; aw += w * v.w;
    }
    float4 o; o.x = ax; o.y = ay; o.z = az; o.w = aw;
    ((float4*)out)[(size_t)i * 1024 + p4] = o;
}

extern "C" void kernel_launch(void* const* d_in, const int* in_sizes, int n_in,
                              void* d_out, int out_size, void* d_ws, size_t ws_size,
                              hipStream_t stream) {
    (void)in_sizes; (void)n_in; (void)out_size; (void)ws_size;
    const float* M     = (const float*)d_in[0];
    const float* r     = (const float*)d_in[1];
    const float* cpart = (const float*)d_in[2];
    const float* x     = (const float*)d_in[3];
    float* out = (float*)d_out;
    float* ws  = (float*)d_ws;

    float* LU = ws;                 // 512*512
    float* A  = ws + 262144;        // 512*512 (original A, kept for refinement)
    float* W  = ws + 524288;        // 512*12
    float* R  = ws + 530432;        // 512*12
    float* partials = out;          // 8 x 512*512 floats = exactly the 8 MiB output buffer

    // Stage 1: A = constant_part + sum_e r[e] M[e]
    k_partial<<<dim3(256, NCHUNK), 256, 0, stream>>>(M, r, partials);
    k_combine<<<dim3(256), 256, 0, stream>>>(partials, cpart, A, LU);

    // Stage 2: blocked LU (no pivoting), NB = 64
    for (int p = 0; p < 8; ++p) {
        int k0 = p * 64;
        k_panel<<<dim3(1), 1024, 0, stream>>>(LU, k0);
        int nc = NMAT - k0 - 64;
        if (nc > 0) {
            k_trsm<<<dim3(nc / 64), 256, 0, stream>>>(LU, k0);
            k_gemm<<<dim3(nc / 64, nc / 64), 256, 0, stream>>>(LU, k0);
        }
    }

    // Stage 3: W = A^{-1} I[:,500:512], + 2 iterative-refinement steps
    k_solve<<<dim3(MRHS), 64, 0, stream>>>(LU, R /*unused*/, W, 0);
    for (int it = 0; it < 2; ++it) {
        k_resid<<<dim3(NMAT), 64, 0, stream>>>(A, W, R);
        k_solve<<<dim3(MRHS), 64, 0, stream>>>(LU, R, W, 1);
    }

    // Stage 4: out = W @ e
    k_out<<<dim3(4, 512), 256, 0, stream>>>(W, x, out);
}

// Round 4
// 2190.879 us; speedup vs baseline: 1.5297x; 1.5297x over previous
//
#include <hip/hip_runtime.h>
#include <cstddef>

#define NMAT 512
#define MRHS 12
#define NCHUNK 8
#define ECH 128   // 1024 / NCHUNK

// ---------------- Stage 1: partials[chunk] = sum_{e in chunk} r[e] * M[e] ----------------
__global__ void __launch_bounds__(256) k_partial(const float* __restrict__ M,
                                                 const float* __restrict__ r,
                                                 float* __restrict__ partials) {
    __shared__ float rs[ECH];
    const int chunk = blockIdx.y;
    const int idx4 = blockIdx.x * 256 + threadIdx.x;   // float4 index in 512x512
    for (int i = threadIdx.x; i < ECH; i += 256) rs[i] = r[chunk * ECH + i];
    __syncthreads();
    const float4* __restrict__ M4 = (const float4*)M;
    const size_t base = (size_t)chunk * ECH * 65536u + (size_t)idx4;
    float ax = 0.f, ay = 0.f, az = 0.f, aw = 0.f;
#pragma unroll 4
    for (int e = 0; e < ECH; ++e) {
        float4 v = M4[base + (size_t)e * 65536u];
        float rv = rs[e];
        ax += rv * v.x; ay += rv * v.y; az += rv * v.z; aw += rv * v.w;
    }
    float4 o; o.x = ax; o.y = ay; o.z = az; o.w = aw;
    ((float4*)partials)[(size_t)chunk * 65536u + idx4] = o;
}

// ---------------- Stage 1b: A = constant_part + sum_c partials[c]; LU = A ----------------
__global__ void __launch_bounds__(256) k_combine(const float* __restrict__ partials,
                                                 const float* __restrict__ cpart,
                                                 float* __restrict__ A,
                                                 float* __restrict__ LU) {
    const int idx4 = blockIdx.x * 256 + threadIdx.x;
    const float4* p4 = (const float4*)partials;
    float4 a = ((const float4*)cpart)[idx4];
#pragma unroll
    for (int c = 0; c < NCHUNK; ++c) {
        float4 v = p4[(size_t)c * 65536u + idx4];
        a.x += v.x; a.y += v.y; a.z += v.z; a.w += v.w;
    }
    ((float4*)A)[idx4] = a;
    ((float4*)LU)[idx4] = a;
}

// ---------------- LU panel factor (no pivoting), NB=64, register-resident ----------------
// 1 block, 1024 threads = 16 waves. Row i of panel lives on wave (i&15), slot (i>>4),
// lane = column. Rank-1 update: 1 shfl + 1 FMA per row per j. Pivot row broadcast
// through double-buffered LDS row (1 barrier per j).
template <int NR>
__global__ void __launch_bounds__(1024) k_panel(float* __restrict__ LU, int k0) {
    constexpr int NS = NR / 16;
    __shared__ float piv[2][64];
    const int tid = threadIdx.x;
    const int w = tid >> 6, lane = tid & 63;
    float reg[NS];
#pragma unroll
    for (int s = 0; s < NS; ++s) {
        int i = s * 16 + w;
        reg[s] = LU[(size_t)(k0 + i) * NMAT + k0 + lane];
    }
    for (int j = 0; j < 64; ++j) {
        if (w == (j & 15)) {
#pragma unroll
            for (int s = 0; s < 4; ++s)
                if ((j >> 4) == s) piv[j & 1][lane] = reg[s];
        }
        __syncthreads();
        float pvl = piv[j & 1][lane];
        float pj = __shfl(pvl, j);
        float pivinv = 1.0f / pj;
#pragma unroll
        for (int s = 0; s < NS; ++s) {
            int i = s * 16 + w;
            if (i > j) {               // wave-uniform branch
                float rv = reg[s];
                float l = __shfl(rv, j) * pivinv;
                float upd = rv - l * pvl;
                rv = (lane > j) ? upd : rv;
                rv = (lane == j) ? l : rv;
                reg[s] = rv;
            }
        }
    }
#pragma unroll
    for (int s = 0; s < NS; ++s) {
        int i = s * 16 + w;
        LU[(size_t)(k0 + i) * NMAT + k0 + lane] = reg[s];
    }
}

// ---------------- U12 = L11^{-1} A12 via forward SUBSTITUTION (stable), per 64-col tile ----
// Race-free in-place: each block owns its column tile (reads+writes only rows k0..k1,
// cols jc0..jc0+63 of LU plus the read-only L11 panel block).
__global__ void __launch_bounds__(256) k_trsm(float* __restrict__ LU, int k0) {
    __shared__ float L11[64 * 65];
    __shared__ float Y[64 * 65];
    const int k1 = k0 + 64;
    const int jc0 = k1 + blockIdx.x * 64;
    const int tid = threadIdx.x;
    for (int idx = tid; idx < 4096; idx += 256) {
        int i = idx >> 6, c = idx & 63;
        L11[i * 65 + c] = LU[(size_t)(k0 + i) * NMAT + k0 + c];
        Y[i * 65 + c]   = LU[(size_t)(k0 + i) * NMAT + jc0 + c];
    }
    __syncthreads();
    const int c = tid & 63, ib = tid >> 6;  // ib 0..3
    for (int t = 0; t < 64; ++t) {
        float yt = Y[t * 65 + c];
        for (int i = ib; i < 64; i += 4)
            if (i > t) Y[i * 65 + c] -= L11[i * 65 + t] * yt;
        __syncthreads();
    }
    for (int idx = tid; idx < 4096; idx += 256) {
        int i = idx >> 6, cc = idx & 63;
        LU[(size_t)(k0 + i) * NMAT + jc0 + cc] = Y[i * 65 + cc];
    }
}

// ---------------- A22 -= L21 @ U12, 64x64 tiles, 4x4 per thread (proven R1) ----------------
__global__ void __launch_bounds__(256) k_gemm(float* __restrict__ LU, int k0) {
    __shared__ float L21[64 * 65];
    __shared__ float Ys[64 * 65];
    const int k1 = k0 + 64;
    const int jc0 = k1 + blockIdx.x * 64;
    const int r0  = k1 + blockIdx.y * 64;
    const int tid = threadIdx.x;
    for (int idx = tid; idx < 4096; idx += 256) {
        int i = idx >> 6, c = idx & 63;
        L21[i * 65 + c] = LU[(size_t)(r0 + i) * NMAT + k0 + c];
        Ys[i * 65 + c]  = LU[(size_t)(k0 + i) * NMAT + jc0 + c];
    }
    __syncthreads();
    const int trow = tid >> 4, tcol = tid & 15;
    float acc[4][4];
#pragma unroll
    for (int rr = 0; rr < 4; ++rr) {
        float4 v = *(const float4*)&LU[(size_t)(r0 + 4 * trow + rr) * NMAT + jc0 + 4 * tcol];
        acc[rr][0] = v.x; acc[rr][1] = v.y; acc[rr][2] = v.z; acc[rr][3] = v.w;
    }
#pragma unroll 4
    for (int kk = 0; kk < 64; ++kk) {
        float b0 = Ys[kk * 65 + 4 * tcol + 0];
        float b1 = Ys[kk * 65 + 4 * tcol + 1];
        float b2 = Ys[kk * 65 + 4 * tcol + 2];
        float b3 = Ys[kk * 65 + 4 * tcol + 3];
#pragma unroll
        for (int rr = 0; rr < 4; ++rr) {
            float a = L21[(4 * trow + rr) * 65 + kk];
            acc[rr][0] -= a * b0; acc[rr][1] -= a * b1;
            acc[rr][2] -= a * b2; acc[rr][3] -= a * b3;
        }
    }
#pragma unroll
    for (int rr = 0; rr < 4; ++rr) {
        float4 v; v.x = acc[rr][0]; v.y = acc[rr][1]; v.z = acc[rr][2]; v.w = acc[rr][3];
        *(float4*)&LU[(size_t)(r0 + 4 * trow + rr) * NMAT + jc0 + 4 * tcol] = v;
    }
}

// ---------------- LUT = LU^T + reciprocal diag ----------------
__global__ void __launch_bounds__(256) k_transpose(const float* __restrict__ LU,
                                                   float* __restrict__ LUT,
                                                   float* __restrict__ dinv) {
    __shared__ float t[32][33];
    const int bx = blockIdx.x, by = blockIdx.y;
    const int tid = threadIdx.x;
    const int lx = tid & 31, ly = tid >> 5;
    for (int yy = ly; yy < 32; yy += 8)
        t[yy][lx] = LU[(size_t)(by * 32 + yy) * NMAT + bx * 32 + lx];
    __syncthreads();
    for (int yy = ly; yy < 32; yy += 8)
        LUT[(size_t)(bx * 32 + yy) * NMAT + by * 32 + lx] = t[lx][yy];
    if (bx == by && tid < 32) dinv[bx * 32 + tid] = 1.0f / t[tid][tid];
}

// ---------------- triangular solves, 12 RHS, 1 wave per RHS, coalesced column loads ----------
// mode 0: b = e_{500+c}, W = x (forward collapses to last diag block: L^{-1}e_k is
// supported on rows >= k >= 500). mode 1: b = B[:,c], W += x.
__global__ void __launch_bounds__(64) k_solve(const float* __restrict__ LUT,
                                              const float* __restrict__ dinv,
                                              const float* __restrict__ B,
                                              float* __restrict__ W, int mode) {
    const int c = blockIdx.x;
    const int lane = threadIdx.x;
    float y[8];
    if (mode) {
#pragma unroll
        for (int s = 0; s < 8; ++s) y[s] = B[(s * 64 + lane) * MRHS + c];
#pragma unroll
        for (int js = 0; js < 8; ++js) {
#pragma unroll 4
            for (int jl = 0; jl < 64; ++jl) {
                const int j = js * 64 + jl;
                const float* __restrict__ col = &LUT[(size_t)j * NMAT];
                float yj = __shfl(y[js], jl);
                if (lane > jl) y[js] -= col[js * 64 + lane] * yj;
#pragma unroll
                for (int s = js + 1; s < 8; ++s) y[s] -= col[s * 64 + lane] * yj;
            }
        }
    } else {
#pragma unroll
        for (int s = 0; s < 8; ++s) y[s] = 0.f;
        y[7] = (lane == 52 + c) ? 1.0f : 0.0f;
        for (int jl = 52; jl < 63; ++jl) {
            const float* __restrict__ col = &LUT[(size_t)(448 + jl) * NMAT];
            float yj = __shfl(y[7], jl);
            if (lane > jl) y[7] -= col[448 + lane] * yj;
        }
    }
    // backward: U x = y
#pragma unroll
    for (int js = 7; js >= 0; --js) {
#pragma unroll 4
        for (int jl = 63; jl >= 0; --jl) {
            const int j = js * 64 + jl;
            const float* __restrict__ col = &LUT[(size_t)j * NMAT];
            float xj = __shfl(y[js], jl) * dinv[j];
            float t = y[js] - col[js * 64 + lane] * xj;
            y[js] = (lane < jl) ? t : ((lane == jl) ? xj : y[js]);
#pragma unroll
            for (int s = 0; s < js; ++s) y[s] -= col[s * 64 + lane] * xj;
        }
    }
#pragma unroll
    for (int s = 0; s < 8; ++s) {
        int row = s * 64 + lane;
        if (mode) W[row * MRHS + c] += y[s];
        else      W[row * MRHS + c] = y[s];
    }
}

// ---------------- residual R = I[:,500:512] - A @ W  (f64 accumulate) ----------------
__global__ void __launch_bounds__(64) k_resid(const float* __restrict__ A,
                                              const float* __restrict__ W,
                                              float* __restrict__ R) {
    const int row = blockIdx.x;
    const int lane = threadIdx.x;
    double acc[MRHS];
#pragma unroll
    for (int cc = 0; cc < MRHS; ++cc) acc[cc] = 0.0;
    for (int k = lane; k < NMAT; k += 64) {
        float a = A[(size_t)row * NMAT + k];
#pragma unroll
        for (int cc = 0; cc < MRHS; ++cc) acc[cc] += (double)a * (double)W[k * MRHS + cc];
    }
#pragma unroll
    for (int cc = 0; cc < MRHS; ++cc) {
        double v = acc[cc];
#pragma unroll
        for (int off = 32; off > 0; off >>= 1) v += __shfl_xor(v, off);
        if (lane == cc) R[row * MRHS + cc] = (float)(((row == 500 + cc) ? 1.0 : 0.0) - v);
    }
}

// ---------------- out[i][p] = sum_k W[i][k] * e[k][p] ----------------
__global__ void __launch_bounds__(256) k_out(const float* __restrict__ W,
                                             const float* __restrict__ x,
                                             float* __restrict__ out) {
    const int p4 = blockIdx.x * 256 + threadIdx.x;  // 0..1023
    const int i = blockIdx.y;
    const float4* __restrict__ x4 = (const float4*)x;
    float ax = 0.f, ay = 0.f, az = 0.f, aw = 0.f;
#pragma unroll
    for (int k = 0; k < MRHS; ++k) {
        float w = W[i * MRHS + k];
        float4 v = x4[k * 1024 + p4];
        ax += w * v.x; ay += w * v.y; az += w * v.z; aw += w * v.w;
    }
    float4 o; o.x = ax; o.y = ay; o.z = az; o.w = aw;
    ((float4*)out)[(size_t)i * 1024 + p4] = o;
}

extern "C" void kernel_launch(void* const* d_in, const int* in_sizes, int n_in,
                              void* d_out, int out_size, void* d_ws, size_t ws_size,
                              hipStream_t stream) {
    (void)in_sizes; (void)n_in; (void)out_size; (void)ws_size;
    const float* M     = (const float*)d_in[0];
    const float* r     = (const float*)d_in[1];
    const float* cpart = (const float*)d_in[2];
    const float* x     = (const float*)d_in[3];
    float* out = (float*)d_out;
    float* ws  = (float*)d_ws;

    float* LU   = ws;                 // 262144
    float* A    = ws + 262144;        // 262144
    float* LUT  = ws + 524288;        // 262144
    float* W    = ws + 786432;        // 6144
    float* R    = ws + 792576;        // 6144
    float* dinv = ws + 798720;        // 512
    float* partials = out;            // 8 x 512*512 floats = exactly the output buffer

    // Stage 1: A = constant_part + sum_e r[e] M[e]
    k_partial<<<dim3(256, NCHUNK), 256, 0, stream>>>(M, r, partials);
    k_combine<<<dim3(256), 256, 0, stream>>>(partials, cpart, A, LU);

    // Stage 2: blocked LU (no pivoting), NB = 64.
    // Register-resident panel + substitution trsm (stable) + gemm update.
    for (int p = 0; p < 8; ++p) {
        const int k0 = p * 64;
        switch (p) {
            case 0: k_panel<512><<<1, 1024, 0, stream>>>(LU, k0); break;
            case 1: k_panel<448><<<1, 1024, 0, stream>>>(LU, k0); break;
            case 2: k_panel<384><<<1, 1024, 0, stream>>>(LU, k0); break;
            case 3: k_panel<320><<<1, 1024, 0, stream>>>(LU, k0); break;
            case 4: k_panel<256><<<1, 1024, 0, stream>>>(LU, k0); break;
            case 5: k_panel<192><<<1, 1024, 0, stream>>>(LU, k0); break;
            case 6: k_panel<128><<<1, 1024, 0, stream>>>(LU, k0); break;
            case 7: k_panel< 64><<<1, 1024, 0, stream>>>(LU, k0); break;
        }
        const int nc = NMAT - k0 - 64;
        if (nc > 0) {
            k_trsm<<<dim3(nc / 64), 256, 0, stream>>>(LU, k0);
            k_gemm<<<dim3(nc / 64, nc / 64), 256, 0, stream>>>(LU, k0);
        }
    }

    // Stage 2b: transposed copy for coalesced substitution + reciprocal diagonal
    k_transpose<<<dim3(16, 16), 256, 0, stream>>>(LU, LUT, dinv);

    // Stage 3: W = A^{-1} I[:,500:512], + 3 iterative-refinement steps
    k_solve<<<dim3(MRHS), 64, 0, stream>>>(LUT, dinv, R /*unused*/, W, 0);
    for (int it = 0; it < 3; ++it) {
        k_resid<<<dim3(NMAT), 64, 0, stream>>>(A, W, R);
        k_solve<<<dim3(MRHS), 64, 0, stream>>>(LUT, dinv, R, W, 1);
    }

    // Stage 4: out = W @ e
    k_out<<<dim3(4, 512), 256, 0, stream>>>(W, x, out);
}